// Round 9
// baseline (413.650 us; speedup 1.0000x reference)
//
#include <hip/hip_runtime.h>
#include <hip/hip_bf16.h>

// 4-layer SRU. L=4, B=32, T=512, D=512, V=1000. f32 inputs, f32 output.
// R21: gemm reverted to R16's exact kernel (41.9us measured; 4 schedule
// variants all 41-44us -> stop rescheduling). Scan restructured: ONE
// fused compute wave per block (c-chain + h-path + stores inline; h ops
// fill exp2/rcp stall slots as ILP; ring buffer GONE) + 2 producer waves
// staging the 4 operand streams into double-buffered LDS via
// global_load_lds (R16's proven pattern). SB=64 -> 8 phases, half the
// barriers. Producers vmcnt(0)-drain before each s_barrier (~600cyc,
// hidden under compute wave's ~3k-cyc phase). Fused math = R19's (passed,
// same absmax). 192-thread blocks, 66KiB LDS, 256 blocks.

#define LAYERS 4
#define BB 32
#define TT 512
#define DD 512
#define N3 1536
#define MROWS (TT * BB)
#define WPL ((size_t)DD * N3)
#define SB2 64                  // steps per phase (scan)
#define LOG2E 1.4426950408889634f
#define TWOLOG2E 2.8853900817779268f

typedef unsigned short u16;
typedef unsigned int u32;
typedef _Float16 half8 __attribute__((ext_vector_type(8)));
typedef float f32x4 __attribute__((ext_vector_type(4)));

#define SBAR() asm volatile("s_barrier" ::: "memory")
#define WAITVM(n) asm volatile("s_waitcnt vmcnt(" n ")" ::: "memory")

__device__ __forceinline__ float b2f(u16 u) {
  union { unsigned int i; float f; } x;
  x.i = ((unsigned int)u) << 16;
  return x.f;
}
__device__ __forceinline__ u16 f2h(float f) {
  _Float16 h = (_Float16)f;
  return *(u16*)&h;
}
__device__ __forceinline__ float h2f(u16 u) {
  _Float16 h;
  *(u16*)&h = u;
  return (float)h;
}
__device__ __forceinline__ float rcpf(float x) { return __builtin_amdgcn_rcpf(x); }
__device__ __forceinline__ float exp2f_(float x) { return __builtin_amdgcn_exp2f(x); }

__device__ __forceinline__ void async_ld16(const void* g, void* l) {
  __builtin_amdgcn_global_load_lds(
      (const __attribute__((address_space(1))) void*)g,
      (__attribute__((address_space(3))) void*)l, 16, 0, 0);
}
__device__ __forceinline__ void async_ld4(const void* g, void* l) {
  __builtin_amdgcn_global_load_lds(
      (const __attribute__((address_space(1))) void*)g,
      (__attribute__((address_space(3))) void*)l, 4, 0, 0);
}

// ---- dtype detection (flags[0]: floats f32, [1]: mask bytes, [2]: ids int64)
__global__ void detect_kernel(const u16* __restrict__ emb_u,
                              const int* __restrict__ mask_i,
                              const int* __restrict__ ids_i,
                              int* __restrict__ flags) {
  __shared__ int cnt[3];
  __shared__ int zc;
  int tid = threadIdx.x;
  if (tid < 3) cnt[tid] = 0;
  if (tid == 0) zc = 0;
  __syncthreads();
  int bad = 0, zero_even = 0;
  for (int i = tid; i < 8192; i += 256) {
    u16 u = emb_u[i];
    unsigned e = (u >> 7) & 0xFF;
    if (e >= 0x8F) bad++;
    if ((i & 1) == 0 && u == 0) zero_even++;
  }
  if (bad) atomicAdd(&cnt[0], bad);
  if (zero_even) atomicAdd(&zc, zero_even);
  if (tid < 64) {
    unsigned vv = (unsigned)mask_i[tid];
    if (vv > 1u) atomicAdd(&cnt[1], 1);
  }
  if (tid < 256) {
    if (ids_i[2 * tid + 1] == 0) atomicAdd(&cnt[2], 1);
  }
  __syncthreads();
  if (tid == 0) {
    flags[0] = (cnt[0] > 64 || zc > 3000) ? 1 : 0;
    flags[1] = (cnt[1] > 0) ? 1 : 0;
    flags[2] = (cnt[2] >= 192) ? 1 : 0;
  }
}

// ---- W -> f16 transpose: W16[l][n][k] ----------------------------------
__global__ __launch_bounds__(256)
void wprep_kernel(const void* __restrict__ W, u16* __restrict__ W16,
                  const int* __restrict__ flags) {
  __shared__ float tileW[32][33];
  int l = blockIdx.z;
  int k0 = blockIdx.x * 32;
  int n0 = blockIdx.y * 32;
  int tx = threadIdx.x & 31;
  int ty = threadIdx.x >> 5;
  int ff = flags[0];
  const float* Wf = (const float*)W + (size_t)l * WPL;
  const u16* Wb = (const u16*)W + (size_t)l * WPL;
  for (int kk = ty; kk < 32; kk += 8) {
    size_t off = (size_t)(k0 + kk) * N3 + n0 + tx;
    tileW[kk][tx] = ff ? Wf[off] : b2f(Wb[off]);
  }
  __syncthreads();
  u16* outP = W16 + (size_t)l * WPL;
  for (int nn = ty; nn < 32; nn += 8) {
    float x = tileW[tx][nn];
    outP[(size_t)(n0 + nn) * DD + k0 + tx] = f2h(x);
  }
}

// ---- embedding: X16 f16 (T,B,D) only -----------------------------------
__global__ void embed_kernel(const int* __restrict__ ids,
                             const void* __restrict__ emb,
                             u16* __restrict__ X16,
                             const int* __restrict__ flags) {
  int i = blockIdx.x * 256 + threadIdx.x;  // (t,b,d) linear
  int d = i & (DD - 1);
  int tb = i >> 9;
  int b = tb & (BB - 1);
  int t = tb >> 5;
  int ii = b * TT + t;
  int id = flags[2] ? ids[2 * ii] : ids[ii];
  float val = flags[0] ? ((const float*)emb)[id * DD + d]
                       : b2f(((const u16*)emb)[id * DD + d]);
  X16[i] = f2h(val);
}

// ---- MFMA fp16 GEMM: 256x128 tile, 4 waves, triple-buffer BK=32 --------
// (R16 verbatim: 41.9us measured, 0 bank conflicts.)
__global__ __launch_bounds__(256, 2)
void gemm_kernel(const u16* __restrict__ X16, const u16* __restrict__ W16l,
                 const void* __restrict__ bvec, int layer,
                 const int* __restrict__ flags,
                 u16* __restrict__ U16, int row_base, int chunkM, int nblk) {
  __shared__ u16 ldsA[3][8192];  // [slot][16 blocks x 512 u16] = 48 KiB
  __shared__ u16 ldsB[3][4096];  // [slot][ 8 blocks x 512 u16] = 24 KiB
  const int tid = threadIdx.x;
  const int lane = tid & 63, wave = tid >> 6;
  const int wm = wave >> 1, wn = wave & 1;
  const int m16 = lane & 15, quad = lane >> 4;

  // bijective XCD swizzle (nblk % 8 == 0 for all chunk sizes)
  const int orig = blockIdx.x;
  const int wg = (orig & 7) * (nblk >> 3) + (orig >> 3);
  const int mt = wg / 12, nt = wg - mt * 12;

  const int arow0 = row_base + mt * 256;
  const int bcol0 = nt * 128;

  const int srow = lane >> 2;
  const int sq = (lane & 3) ^ ((lane >> 3) & 3);   // inverse swizzle
  const u16* pa = X16 + (size_t)(arow0 + wave * 64 + srow) * DD + sq * 8;
  const u16* pb = W16l + (size_t)(bcol0 + wave * 32 + srow) * DD + sq * 8;

  auto stage = [&](int t) {   // K-tile t -> slot t%3; 6 loads/wave
    const int sl = t % 3;
    const int kv = t * 32;
    u16* da = &ldsA[sl][(wave * 4) * 512];
    const u16* sa = pa + kv;
#pragma unroll
    for (int j = 0; j < 4; ++j)
      async_ld16(sa + (size_t)16 * j * DD, da + j * 512);
    u16* db_ = &ldsB[sl][(wave * 2) * 512];
    const u16* sb = pb + kv;
#pragma unroll
    for (int j = 0; j < 2; ++j)
      async_ld16(sb + (size_t)16 * j * DD, db_ + j * 512);
  };

  f32x4 acc[8][4];
#pragma unroll
  for (int mi = 0; mi < 8; ++mi)
#pragma unroll
    for (int ni = 0; ni < 4; ++ni)
#pragma unroll
      for (int r = 0; r < 4; ++r) acc[mi][ni][r] = 0.f;

  stage(0); stage(1);
  WAITVM("6");   // tile 0 landed (tile 1 in flight)
  SBAR();

  const int loff = m16 * 32 + (quad ^ ((m16 >> 1) & 3)) * 8;

#pragma unroll
  for (int t = 0; t < 16; ++t) {
    const int sl = t % 3;
    half8 af[8], bf[4];
#pragma unroll
    for (int i = 0; i < 8; ++i)
      af[i] = *(const half8*)&ldsA[sl][(wm * 8 + i) * 512 + loff];
#pragma unroll
    for (int i = 0; i < 4; ++i)
      bf[i] = *(const half8*)&ldsB[sl][(wn * 4 + i) * 512 + loff];
    if (t + 2 < 16) stage(t + 2);
    __builtin_amdgcn_s_setprio(1);
#pragma unroll
    for (int mi = 0; mi < 8; ++mi)
#pragma unroll
      for (int ni = 0; ni < 4; ++ni)
        acc[mi][ni] = __builtin_amdgcn_mfma_f32_16x16x32_f16(
            af[mi], bf[ni], acc[mi][ni], 0, 0, 0);
    __builtin_amdgcn_s_setprio(0);
    if (t <= 13) WAITVM("6");        // tile t+1 landed (t+2 in flight)
    else if (t == 14) WAITVM("0");   // last tile landed
    if (t < 15) SBAR();
  }

  // epilogue: plane and transform are block-uniform (128-col tile)
  const int ff = flags[0];
  const int pl = nt >> 2;               // plane 0..2
  const int dd0 = (nt & 3) * 128;
  u16* up = U16 + (size_t)pl * chunkM * 512;
  const int r0 = mt * 256 + wm * 128 + quad * 4;
  const int c0 = dd0 + wn * 64 + m16;
  if (pl == 0) {
#pragma unroll
    for (int mi = 0; mi < 8; ++mi)
#pragma unroll
      for (int reg = 0; reg < 4; ++reg) {
        size_t rb = (size_t)(r0 + mi * 16 + reg) * 512 + c0;
#pragma unroll
        for (int ni = 0; ni < 4; ++ni)
          up[rb + ni * 16] = f2h(acc[mi][ni][reg]);
      }
  } else {
    float bias[4];
#pragma unroll
    for (int ni = 0; ni < 4; ++ni) {
      size_t bo = (size_t)layer * 2 * DD + (size_t)(pl - 1) * DD + c0 + ni * 16;
      bias[ni] = ff ? ((const float*)bvec)[bo] : b2f(((const u16*)bvec)[bo]);
    }
#pragma unroll
    for (int mi = 0; mi < 8; ++mi)
#pragma unroll
      for (int reg = 0; reg < 4; ++reg) {
        size_t rb = (size_t)(r0 + mi * 16 + reg) * 512 + c0;
#pragma unroll
        for (int ni = 0; ni < 4; ++ni)
          up[rb + ni * 16] = f2h(-(acc[mi][ni][reg] + bias[ni]) * LOG2E);
      }
  }
}

// ---- SRU scan: fused compute wave + 2 producer waves, SB2=64 -----------
// wave0: full per-step compute (c-chain; h ops fill chain stalls as ILP;
// stores inline; NO ring). wave1: xt/fps streams; wave2: rps/xi streams.
// Double-buffered LDS (parity k&1); producers vmcnt(0)-drain before each
// barrier (hidden under wave0's longer phase). Fused math = R19 (passed).
template <int EMIT>
__global__ __launch_bounds__(192, 1)
void scan_kernel(const u16* __restrict__ U16, float* __restrict__ X,
                 u16* __restrict__ X16,
                 const void* __restrict__ mask_p, const void* __restrict__ vbase,
                 int layer, const int* __restrict__ flags,
                 float* __restrict__ carry, int t0, int nt, int chunkM) {
  __shared__ u16 bufA[2][2][SB2][64];   // [parity][xt|fps][step][lane]
  __shared__ u16 bufB[2][2][SB2][64];   // [parity][rps|xi][step][lane]
  __shared__ int msk[TT];
  const int tid = threadIdx.x;
  const int wave = tid >> 6, lane = tid & 63;
  const int idx0 = blockIdx.x * 64;  // chain base in [0, B*D)
  const int b = idx0 >> 9;           // one b per block
  const int d0 = idx0 & 511;
  const int ff = flags[0], fm = flags[1];

  const int* mi_ = (const int*)mask_p + b * TT;
  const unsigned char* mb_ = (const unsigned char*)mask_p + b * TT;
  for (int i = tid; i < nt; i += 192) msk[i] = fm ? (int)mb_[t0 + i] : mi_[t0 + i];

  float vfs = 0.f, vrs = 0.f, c = 0.f;
  if (wave == 0) {
    int d = d0 + lane;
    size_t voff = (size_t)layer * 2 * DD;
    float vf = ff ? ((const float*)vbase)[voff + d]
                  : b2f(((const u16*)vbase)[voff + d]);
    float vr = ff ? ((const float*)vbase)[voff + DD + d]
                  : b2f(((const u16*)vbase)[voff + DD + d]);
    vfs = -vf * LOG2E;
    vrs = -vr * LOG2E;
    c = (t0 == 0) ? 0.f : carry[idx0 + lane];
  }

  const int nbuf = nt / SB2;

  // u16-stream pair load: lanes 0-31 -> step s, lanes 32-63 -> step s+1
  auto ld_pair = [&](const u16* rowS, const u16* rowS1, void* ldst) {
    const u32* a0 = (const u32*)rowS;
    const u32* a1 = (const u32*)rowS1;
    const u32* ga = (lane < 32) ? (a0 + lane) : (a1 + (lane - 32));
    async_ld4(ga, ldst);
  };

  auto produceA = [&](int k) {  // wave1: xt (plane0) + fps (plane1)
    int ph = k & 1, tl = k * SB2;
    const u16* p0 = U16 + ((size_t)tl * BB + b) * 512 + d0;
    const u16* p1 = p0 + (size_t)chunkM * 512;
#pragma unroll
    for (int s = 0; s < SB2; s += 2)
      ld_pair(p0 + (size_t)s * BB * 512, p0 + (size_t)(s + 1) * BB * 512,
              &bufA[ph][0][s][0]);
#pragma unroll
    for (int s = 0; s < SB2; s += 2)
      ld_pair(p1 + (size_t)s * BB * 512, p1 + (size_t)(s + 1) * BB * 512,
              &bufA[ph][1][s][0]);
  };
  auto produceB = [&](int k) {  // wave2: rps (plane2) + xi (X16)
    int ph = k & 1, tl = k * SB2;
    const u16* p2 = U16 + 2 * (size_t)chunkM * 512 + ((size_t)tl * BB + b) * 512 + d0;
    const u16* xb = X16 + ((size_t)(t0 + tl) * BB + b) * DD + d0;
#pragma unroll
    for (int s = 0; s < SB2; s += 2)
      ld_pair(p2 + (size_t)s * BB * 512, p2 + (size_t)(s + 1) * BB * 512,
              &bufB[ph][0][s][0]);
#pragma unroll
    for (int s = 0; s < SB2; s += 2)
      ld_pair(xb + (size_t)s * BB * DD, xb + (size_t)(s + 1) * BB * DD,
              &bufB[ph][1][s][0]);
  };

  const size_t SU = (size_t)BB * 512;   // u16 stride per timestep
  u16* pxw = X16 + ((size_t)t0 * BB + b) * DD + d0 + lane;
  float* pX = X + ((size_t)b * TT + t0) * DD + d0 + lane;

  // prologue: fill phase-0 buffers; __syncthreads drains producers' loads
  if (wave == 1) produceA(0);
  if (wave == 2) produceB(0);
  __syncthreads();

  for (int k = 0; k < nbuf; ++k) {
    if (wave == 1) {
      if (k + 1 < nbuf) produceA(k + 1);
      WAITVM("0");
      SBAR();
    } else if (wave == 2) {
      if (k + 1 < nbuf) produceB(k + 1);
      WAITVM("0");
      SBAR();
    } else {
      const int ph = k & 1;
      const int tb0 = k * SB2;
#pragma unroll 8
      for (int s = 0; s < SB2; ++s) {
        const float xt = h2f(bufA[ph][0][s][lane]);
        const float fps = h2f(bufA[ph][1][s][lane]);  // -(fp+bf)*log2e
        const float rps = h2f(bufB[ph][0][s][lane]);  // -(rp+br)*log2e
        const float xi = h2f(bufB[ph][1][s][lane]);
        const int m = msk[tb0 + s];
        const float tf = exp2f_(fmaf(vfs, c, fps));
        const float f = rcpf(1.f + tf);
        const float cn = fmaf(f, c - xt, xt);
        const float tr = exp2f_(fmaf(vrs, c, rps));   // r-gate uses c_prev
        const float r = rcpf(1.f + tr);
        const float e2 = exp2f_(cn * TWOLOG2E);
        const float th = fmaf(-2.f, rcpf(e2 + 1.f), 1.f);
        const float h = fmaf(r, th - xi, xi);
        const float hout = (m == 0) ? 0.f : h;
        const int tg = tb0 + s;
        if (EMIT) pxw[(size_t)tg * SU] = f2h(hout);
        else pX[(size_t)tg * DD] = hout;
        c = (m == 0) ? c : cn;
      }
      SBAR();
    }
  }
  if (wave == 0) carry[idx0 + lane] = c;
}

__global__ void sentinel_kernel(float* out) { out[threadIdx.x] = 12345.f; }

extern "C" void kernel_launch(void* const* d_in, const int* in_sizes, int n_in,
                              void* d_out, int out_size, void* d_ws, size_t ws_size,
                              hipStream_t stream) {
  const int* ids = (const int*)d_in[0];
  const void* mask = d_in[1];
  const void* emb = d_in[2];
  const void* W = d_in[3];
  const void* v = d_in[4];
  const void* bp = d_in[5];

  char* ws = (char*)d_ws;
  int* flags = (int*)ws;                      // 4 KiB
  float* carry = (float*)(ws + 4096);         // 64 KiB
  const size_t offX16 = 69632;
  const size_t offW16 = offX16 + (size_t)MROWS * DD * 2;   // +16 MiB
  const size_t offU = offW16 + (size_t)LAYERS * WPL * 2;   // +6 MiB
  const size_t perT = (size_t)BB * N3 * 2;    // 98304 B / timestep (3 f16 planes)

  const int cand[4] = {512, 256, 128, 64};  // multiples of SB2
  int chunkT = 0;
  for (int i = 0; i < 4; ++i) {
    if (ws_size >= offU + (size_t)cand[i] * perT) { chunkT = cand[i]; break; }
  }
  if (!chunkT) {
    sentinel_kernel<<<1, 256, 0, stream>>>((float*)d_out);
    return;
  }
  const int chunkM = chunkT * BB;

  u16* X16 = (u16*)(ws + offX16);
  u16* W16 = (u16*)(ws + offW16);
  u16* U16 = (u16*)(ws + offU);
  float* X = (float*)d_out;  // (B,T,D) f32 — final output only

  detect_kernel<<<1, 256, 0, stream>>>((const u16*)emb, (const int*)mask,
                                       (const int*)ids, flags);
  wprep_kernel<<<dim3(16, 48, 4), 256, 0, stream>>>(W, W16, flags);
  embed_kernel<<<MROWS * DD / 256, 256, 0, stream>>>(ids, emb, X16, flags);

  int nch = TT / chunkT;
  for (int l = 0; l < LAYERS; ++l) {
    const u16* W16l = W16 + (size_t)l * WPL;
    for (int ch = 0; ch < nch; ++ch) {
      int t0 = ch * chunkT;
      int nblk = (chunkM / 256) * 12;   // 256x128 tiles; % 8 == 0 always
      gemm_kernel<<<nblk, 256, 0, stream>>>(X16, W16l, bp, l, flags, U16,
                                            t0 * BB, chunkM, nblk);
      if (l < LAYERS - 1)
        scan_kernel<1><<<BB * DD / 64, 192, 0, stream>>>(U16, X, X16, mask, v, l,
                                                         flags, carry, t0, chunkT,
                                                         chunkM);
      else
        scan_kernel<0><<<BB * DD / 64, 192, 0, stream>>>(U16, X, X16, mask, v, l,
                                                         flags, carry, t0, chunkT,
                                                         chunkM);
    }
  }
}

// Round 10
// 336.142 us; speedup vs baseline: 1.2306x; 1.2306x over previous
//
#include <hip/hip_runtime.h>
#include <hip/hip_bf16.h>

// 4-layer SRU. L=4, B=32, T=512, D=512, V=1000. f32 inputs, f32 output.
// R22: revert to the R16 pair (gemm 41.9us + 7-wave scan 37us = 348 best)
// and optimize INSIDE the scan's c-wave, which is the serial critical
// path (~173 cyc/step vs ~30 cyc pure chain): (1) hoist all of the
// phase's LDS reads (32 xt, 32 fps, 32 msk) into registers BEFORE the
// serial chain (fully-unrolled compile-time-indexed arrays -> VGPRs),
// so the chain runs register-only except non-blocking ring ds_writes;
// (2) s_setprio(1) around the chain (T5: c-wave shares a SIMD with h/
// producer waves; it is the block-wide critical path). ~96 extra VGPR on
// a 1-block/CU kernel = free. Everything else R16-verbatim.

#define LAYERS 4
#define BB 32
#define TT 512
#define DD 512
#define N3 1536
#define MROWS (TT * BB)
#define WPL ((size_t)DD * N3)
#define SB 32                   // steps per phase (scan)
#define LOG2E 1.4426950408889634f
#define TWOLOG2E 2.8853900817779268f

typedef unsigned short u16;
typedef unsigned int u32;
typedef _Float16 half8 __attribute__((ext_vector_type(8)));
typedef float f32x4 __attribute__((ext_vector_type(4)));

#define SBAR() asm volatile("s_barrier" ::: "memory")
#define WAITVM(n) asm volatile("s_waitcnt vmcnt(" n ")" ::: "memory")

__device__ __forceinline__ float b2f(u16 u) {
  union { unsigned int i; float f; } x;
  x.i = ((unsigned int)u) << 16;
  return x.f;
}
__device__ __forceinline__ u16 f2h(float f) {
  _Float16 h = (_Float16)f;
  return *(u16*)&h;
}
__device__ __forceinline__ float h2f(u16 u) {
  _Float16 h;
  *(u16*)&h = u;
  return (float)h;
}
__device__ __forceinline__ float rcpf(float x) { return __builtin_amdgcn_rcpf(x); }
__device__ __forceinline__ float exp2f_(float x) { return __builtin_amdgcn_exp2f(x); }

__device__ __forceinline__ void async_ld16(const void* g, void* l) {
  __builtin_amdgcn_global_load_lds(
      (const __attribute__((address_space(1))) void*)g,
      (__attribute__((address_space(3))) void*)l, 16, 0, 0);
}
__device__ __forceinline__ void async_ld4(const void* g, void* l) {
  __builtin_amdgcn_global_load_lds(
      (const __attribute__((address_space(1))) void*)g,
      (__attribute__((address_space(3))) void*)l, 4, 0, 0);
}

// ---- dtype detection (flags[0]: floats f32, [1]: mask bytes, [2]: ids int64)
__global__ void detect_kernel(const u16* __restrict__ emb_u,
                              const int* __restrict__ mask_i,
                              const int* __restrict__ ids_i,
                              int* __restrict__ flags) {
  __shared__ int cnt[3];
  __shared__ int zc;
  int tid = threadIdx.x;
  if (tid < 3) cnt[tid] = 0;
  if (tid == 0) zc = 0;
  __syncthreads();
  int bad = 0, zero_even = 0;
  for (int i = tid; i < 8192; i += 256) {
    u16 u = emb_u[i];
    unsigned e = (u >> 7) & 0xFF;
    if (e >= 0x8F) bad++;
    if ((i & 1) == 0 && u == 0) zero_even++;
  }
  if (bad) atomicAdd(&cnt[0], bad);
  if (zero_even) atomicAdd(&zc, zero_even);
  if (tid < 64) {
    unsigned vv = (unsigned)mask_i[tid];
    if (vv > 1u) atomicAdd(&cnt[1], 1);
  }
  if (tid < 256) {
    if (ids_i[2 * tid + 1] == 0) atomicAdd(&cnt[2], 1);
  }
  __syncthreads();
  if (tid == 0) {
    flags[0] = (cnt[0] > 64 || zc > 3000) ? 1 : 0;
    flags[1] = (cnt[1] > 0) ? 1 : 0;
    flags[2] = (cnt[2] >= 192) ? 1 : 0;
  }
}

// ---- W -> f16 transpose: W16[l][n][k] ----------------------------------
__global__ __launch_bounds__(256)
void wprep_kernel(const void* __restrict__ W, u16* __restrict__ W16,
                  const int* __restrict__ flags) {
  __shared__ float tileW[32][33];
  int l = blockIdx.z;
  int k0 = blockIdx.x * 32;
  int n0 = blockIdx.y * 32;
  int tx = threadIdx.x & 31;
  int ty = threadIdx.x >> 5;
  int ff = flags[0];
  const float* Wf = (const float*)W + (size_t)l * WPL;
  const u16* Wb = (const u16*)W + (size_t)l * WPL;
  for (int kk = ty; kk < 32; kk += 8) {
    size_t off = (size_t)(k0 + kk) * N3 + n0 + tx;
    tileW[kk][tx] = ff ? Wf[off] : b2f(Wb[off]);
  }
  __syncthreads();
  u16* outP = W16 + (size_t)l * WPL;
  for (int nn = ty; nn < 32; nn += 8) {
    float x = tileW[tx][nn];
    outP[(size_t)(n0 + nn) * DD + k0 + tx] = f2h(x);
  }
}

// ---- embedding: X16 f16 (T,B,D) only -----------------------------------
__global__ void embed_kernel(const int* __restrict__ ids,
                             const void* __restrict__ emb,
                             u16* __restrict__ X16,
                             const int* __restrict__ flags) {
  int i = blockIdx.x * 256 + threadIdx.x;  // (t,b,d) linear
  int d = i & (DD - 1);
  int tb = i >> 9;
  int b = tb & (BB - 1);
  int t = tb >> 5;
  int ii = b * TT + t;
  int id = flags[2] ? ids[2 * ii] : ids[ii];
  float val = flags[0] ? ((const float*)emb)[id * DD + d]
                       : b2f(((const u16*)emb)[id * DD + d]);
  X16[i] = f2h(val);
}

// ---- MFMA fp16 GEMM: 256x128 tile, 4 waves, triple-buffer BK=32 --------
// (R16 verbatim: 41.9us measured, 0 bank conflicts.)
__global__ __launch_bounds__(256, 2)
void gemm_kernel(const u16* __restrict__ X16, const u16* __restrict__ W16l,
                 const void* __restrict__ bvec, int layer,
                 const int* __restrict__ flags,
                 u16* __restrict__ U16, int row_base, int chunkM, int nblk) {
  __shared__ u16 ldsA[3][8192];  // [slot][16 blocks x 512 u16] = 48 KiB
  __shared__ u16 ldsB[3][4096];  // [slot][ 8 blocks x 512 u16] = 24 KiB
  const int tid = threadIdx.x;
  const int lane = tid & 63, wave = tid >> 6;
  const int wm = wave >> 1, wn = wave & 1;
  const int m16 = lane & 15, quad = lane >> 4;

  // bijective XCD swizzle (nblk % 8 == 0 for all chunk sizes)
  const int orig = blockIdx.x;
  const int wg = (orig & 7) * (nblk >> 3) + (orig >> 3);
  const int mt = wg / 12, nt = wg - mt * 12;

  const int arow0 = row_base + mt * 256;
  const int bcol0 = nt * 128;

  const int srow = lane >> 2;
  const int sq = (lane & 3) ^ ((lane >> 3) & 3);   // inverse swizzle
  const u16* pa = X16 + (size_t)(arow0 + wave * 64 + srow) * DD + sq * 8;
  const u16* pb = W16l + (size_t)(bcol0 + wave * 32 + srow) * DD + sq * 8;

  auto stage = [&](int t) {   // K-tile t -> slot t%3; 6 loads/wave
    const int sl = t % 3;
    const int kv = t * 32;
    u16* da = &ldsA[sl][(wave * 4) * 512];
    const u16* sa = pa + kv;
#pragma unroll
    for (int j = 0; j < 4; ++j)
      async_ld16(sa + (size_t)16 * j * DD, da + j * 512);
    u16* db_ = &ldsB[sl][(wave * 2) * 512];
    const u16* sb = pb + kv;
#pragma unroll
    for (int j = 0; j < 2; ++j)
      async_ld16(sb + (size_t)16 * j * DD, db_ + j * 512);
  };

  f32x4 acc[8][4];
#pragma unroll
  for (int mi = 0; mi < 8; ++mi)
#pragma unroll
    for (int ni = 0; ni < 4; ++ni)
#pragma unroll
      for (int r = 0; r < 4; ++r) acc[mi][ni][r] = 0.f;

  stage(0); stage(1);
  WAITVM("6");   // tile 0 landed (tile 1 in flight)
  SBAR();

  const int loff = m16 * 32 + (quad ^ ((m16 >> 1) & 3)) * 8;

#pragma unroll
  for (int t = 0; t < 16; ++t) {
    const int sl = t % 3;
    half8 af[8], bf[4];
#pragma unroll
    for (int i = 0; i < 8; ++i)
      af[i] = *(const half8*)&ldsA[sl][(wm * 8 + i) * 512 + loff];
#pragma unroll
    for (int i = 0; i < 4; ++i)
      bf[i] = *(const half8*)&ldsB[sl][(wn * 4 + i) * 512 + loff];
    if (t + 2 < 16) stage(t + 2);
    __builtin_amdgcn_s_setprio(1);
#pragma unroll
    for (int mi = 0; mi < 8; ++mi)
#pragma unroll
      for (int ni = 0; ni < 4; ++ni)
        acc[mi][ni] = __builtin_amdgcn_mfma_f32_16x16x32_f16(
            af[mi], bf[ni], acc[mi][ni], 0, 0, 0);
    __builtin_amdgcn_s_setprio(0);
    if (t <= 13) WAITVM("6");        // tile t+1 landed (t+2 in flight)
    else if (t == 14) WAITVM("0");   // last tile landed
    if (t < 15) SBAR();
  }

  // epilogue: plane and transform are block-uniform (128-col tile)
  const int ff = flags[0];
  const int pl = nt >> 2;               // plane 0..2
  const int dd0 = (nt & 3) * 128;
  u16* up = U16 + (size_t)pl * chunkM * 512;
  const int r0 = mt * 256 + wm * 128 + quad * 4;
  const int c0 = dd0 + wn * 64 + m16;
  if (pl == 0) {
#pragma unroll
    for (int mi = 0; mi < 8; ++mi)
#pragma unroll
      for (int reg = 0; reg < 4; ++reg) {
        size_t rb = (size_t)(r0 + mi * 16 + reg) * 512 + c0;
#pragma unroll
        for (int ni = 0; ni < 4; ++ni)
          up[rb + ni * 16] = f2h(acc[mi][ni][reg]);
      }
  } else {
    float bias[4];
#pragma unroll
    for (int ni = 0; ni < 4; ++ni) {
      size_t bo = (size_t)layer * 2 * DD + (size_t)(pl - 1) * DD + c0 + ni * 16;
      bias[ni] = ff ? ((const float*)bvec)[bo] : b2f(((const u16*)bvec)[bo]);
    }
#pragma unroll
    for (int mi = 0; mi < 8; ++mi)
#pragma unroll
      for (int reg = 0; reg < 4; ++reg) {
        size_t rb = (size_t)(r0 + mi * 16 + reg) * 512 + c0;
#pragma unroll
        for (int ni = 0; ni < 4; ++ni)
          up[rb + ni * 16] = f2h(-(acc[mi][ni][reg] + bias[ni]) * LOG2E);
      }
  }
}

// ---- SRU scan: split-recurrence, 7 waves; c-wave register-hoisted ------
// wave0: c-chain — all phase LDS reads hoisted to VGPRs before the serial
// chain; setprio(1) during the chain. waves1-4: h path (one-phase lag).
// wave5/6: producers (R16 pattern).
template <int EMIT>
__global__ __launch_bounds__(448, 1)
void scan_kernel(const u16* __restrict__ U16, float* __restrict__ X,
                 u16* __restrict__ X16,
                 const void* __restrict__ mask_p, const void* __restrict__ vbase,
                 int layer, const int* __restrict__ flags,
                 float* __restrict__ carry, int t0, int nt, int chunkM) {
  __shared__ u16 bufA[2][2][SB][64];   // [parity][xt|fps][step][lane]
  __shared__ u16 bufB[3][2][SB][64];   // [k%3][rps|xi][step][lane]
  __shared__ float ring[2][2][SB][64]; // [parity][cprev|cn][step][lane]
  __shared__ int msk[TT];
  const int tid = threadIdx.x;
  const int wave = tid >> 6, lane = tid & 63;
  const int idx0 = blockIdx.x * 64;  // chain base in [0, B*D)
  const int b = idx0 >> 9;           // one b per block
  const int d0 = idx0 & 511;
  const int ff = flags[0], fm = flags[1];

  const int* mi_ = (const int*)mask_p + b * TT;
  const unsigned char* mb_ = (const unsigned char*)mask_p + b * TT;
  for (int i = tid; i < nt; i += 448) msk[i] = fm ? (int)mb_[t0 + i] : mi_[t0 + i];

  float vfs = 0.f, vrs = 0.f, c = 0.f;
  {
    int d = d0 + lane;
    size_t voff = (size_t)layer * 2 * DD;
    if (wave == 0) {
      float vf = ff ? ((const float*)vbase)[voff + d]
                    : b2f(((const u16*)vbase)[voff + d]);
      vfs = -vf * LOG2E;
      c = (t0 == 0) ? 0.f : carry[idx0 + lane];
    } else if (wave >= 1 && wave <= 4) {
      float vr = ff ? ((const float*)vbase)[voff + DD + d]
                    : b2f(((const u16*)vbase)[voff + DD + d]);
      vrs = -vr * LOG2E;
    }
  }

  const int nbuf = nt / SB;

  // u16-stream pair load: lanes 0-31 -> step s, lanes 32-63 -> step s+1
  auto ld_pair = [&](const u16* rowS, const u16* rowS1, void* ldst) {
    const u32* a0 = (const u32*)rowS;
    const u32* a1 = (const u32*)rowS1;
    const u32* ga = (lane < 32) ? (a0 + lane) : (a1 + (lane - 32));
    async_ld4(ga, ldst);
  };

  auto produceA = [&](int k) {  // wave5: xt (plane0) + fps (plane1)
    int ph = k & 1, tl = k * SB;
    const u16* p0 = U16 + ((size_t)tl * BB + b) * 512 + d0;
    const u16* p1 = p0 + (size_t)chunkM * 512;
#pragma unroll
    for (int s = 0; s < SB; s += 2)
      ld_pair(p0 + (size_t)s * BB * 512, p0 + (size_t)(s + 1) * BB * 512,
              &bufA[ph][0][s][0]);
#pragma unroll
    for (int s = 0; s < SB; s += 2)
      ld_pair(p1 + (size_t)s * BB * 512, p1 + (size_t)(s + 1) * BB * 512,
              &bufA[ph][1][s][0]);
  };
  auto produceB = [&](int k) {  // wave6: rps (plane2) + xi (X16)
    int ph = k % 3, tl = k * SB;
    const u16* p2 = U16 + 2 * (size_t)chunkM * 512 + ((size_t)tl * BB + b) * 512 + d0;
    const u16* xb = X16 + ((size_t)(t0 + tl) * BB + b) * DD + d0;
#pragma unroll
    for (int s = 0; s < SB; s += 2)
      ld_pair(p2 + (size_t)s * BB * 512, p2 + (size_t)(s + 1) * BB * 512,
              &bufB[ph][0][s][0]);
#pragma unroll
    for (int s = 0; s < SB; s += 2)
      ld_pair(xb + (size_t)s * BB * DD, xb + (size_t)(s + 1) * BB * DD,
              &bufB[ph][1][s][0]);
  };

  float* Xp = X + (size_t)b * TT * DD + d0 + lane;

  // h-wave hw (0..3) handles steps [hw*8, hw*8+8) of phase j
  auto hphase = [&](int j, int hw) {
    int phc = j & 1, phb = j % 3;
    int sbase = hw * (SB / 4);
#pragma unroll
    for (int si = 0; si < SB / 4; ++si) {
      int s = sbase + si;
      float cprev = ring[phc][0][s][lane];
      float cn = ring[phc][1][s][lane];
      float rps = h2f(bufB[phb][0][s][lane]);
      float xin = h2f(bufB[phb][1][s][lane]);
      int m = msk[j * SB + s];
      float tr = exp2f_(fmaf(vrs, cprev, rps));
      float r = rcpf(1.f + tr);
      float e2 = exp2f_(cn * TWOLOG2E);
      float th = fmaf(-2.f, rcpf(e2 + 1.f), 1.f);
      float h = fmaf(r, th - xin, xin);
      float hout = (m == 0) ? 0.f : h;
      int tg = t0 + j * SB + s;
      if (EMIT)
        X16[((size_t)tg * BB + b) * DD + d0 + lane] = f2h(hout);
      else
        Xp[(size_t)tg * DD] = hout;
    }
  };

  if (wave == 5) produceA(0);
  if (wave == 6) produceB(0);

  for (int k = 0; k < nbuf; ++k) {
    __syncthreads();  // phase-k operands ready; ring[k-1] ready
    if (wave == 5) {
      if (k + 1 < nbuf) produceA(k + 1);
    } else if (wave == 6) {
      if (k + 1 < nbuf) produceB(k + 1);
    } else if (wave == 0) {
      const int ph = k & 1;
      // hoist ALL of this phase's LDS reads into registers (compile-time
      // indices -> VGPRs), so the serial chain below is register-only
      // except the non-blocking ring ds_writes.
      float xtv[SB], fpv[SB];
      int mv[SB];
#pragma unroll
      for (int s = 0; s < SB; ++s) {
        xtv[s] = h2f(bufA[ph][0][s][lane]);
        fpv[s] = h2f(bufA[ph][1][s][lane]);
        mv[s] = msk[k * SB + s];
      }
      __builtin_amdgcn_s_setprio(1);
#pragma unroll
      for (int s = 0; s < SB; ++s) {
        float t = exp2f_(fmaf(vfs, c, fpv[s]));
        float f = rcpf(1.f + t);
        float cn = fmaf(f, c - xtv[s], xtv[s]);
        ring[ph][0][s][lane] = c;
        ring[ph][1][s][lane] = cn;
        c = (mv[s] == 0) ? c : cn;
      }
      __builtin_amdgcn_s_setprio(0);
    } else {  // waves 1-4: h path
      if (k > 0) hphase(k - 1, wave - 1);
    }
  }
  __syncthreads();  // last ring phase visible
  if (wave >= 1 && wave <= 4) hphase(nbuf - 1, wave - 1);
  if (wave == 0) carry[idx0 + lane] = c;
}

__global__ void sentinel_kernel(float* out) { out[threadIdx.x] = 12345.f; }

extern "C" void kernel_launch(void* const* d_in, const int* in_sizes, int n_in,
                              void* d_out, int out_size, void* d_ws, size_t ws_size,
                              hipStream_t stream) {
  const int* ids = (const int*)d_in[0];
  const void* mask = d_in[1];
  const void* emb = d_in[2];
  const void* W = d_in[3];
  const void* v = d_in[4];
  const void* bp = d_in[5];

  char* ws = (char*)d_ws;
  int* flags = (int*)ws;                      // 4 KiB
  float* carry = (float*)(ws + 4096);         // 64 KiB
  const size_t offX16 = 69632;
  const size_t offW16 = offX16 + (size_t)MROWS * DD * 2;   // +16 MiB
  const size_t offU = offW16 + (size_t)LAYERS * WPL * 2;   // +6 MiB
  const size_t perT = (size_t)BB * N3 * 2;    // 98304 B / timestep (3 f16 planes)

  const int cand[4] = {512, 256, 128, 64};  // multiples of 2*SB
  int chunkT = 0;
  for (int i = 0; i < 4; ++i) {
    if (ws_size >= offU + (size_t)cand[i] * perT) { chunkT = cand[i]; break; }
  }
  if (!chunkT) {
    sentinel_kernel<<<1, 256, 0, stream>>>((float*)d_out);
    return;
  }
  const int chunkM = chunkT * BB;

  u16* X16 = (u16*)(ws + offX16);
  u16* W16 = (u16*)(ws + offW16);
  u16* U16 = (u16*)(ws + offU);
  float* X = (float*)d_out;  // (B,T,D) f32 — final output only

  detect_kernel<<<1, 256, 0, stream>>>((const u16*)emb, (const int*)mask,
                                       (const int*)ids, flags);
  wprep_kernel<<<dim3(16, 48, 4), 256, 0, stream>>>(W, W16, flags);
  embed_kernel<<<MROWS * DD / 256, 256, 0, stream>>>(ids, emb, X16, flags);

  int nch = TT / chunkT;
  for (int l = 0; l < LAYERS; ++l) {
    const u16* W16l = W16 + (size_t)l * WPL;
    for (int ch = 0; ch < nch; ++ch) {
      int t0 = ch * chunkT;
      int nblk = (chunkM / 256) * 12;   // 256x128 tiles; % 8 == 0 always
      gemm_kernel<<<nblk, 256, 0, stream>>>(X16, W16l, bp, l, flags, U16,
                                            t0 * BB, chunkM, nblk);
      if (l < LAYERS - 1)
        scan_kernel<1><<<BB * DD / 64, 448, 0, stream>>>(U16, X, X16, mask, v, l,
                                                         flags, carry, t0, chunkT,
                                                         chunkM);
      else
        scan_kernel<0><<<BB * DD / 64, 448, 0, stream>>>(U16, X, X16, mask, v, l,
                                                         flags, carry, t0, chunkT,
                                                         chunkM);
    }
  }
}

// Round 11
// 334.823 us; speedup vs baseline: 1.2354x; 1.0039x over previous
//
#include <hip/hip_runtime.h>
#include <hip/hip_bf16.h>

// 4-layer SRU. L=4, B=32, T=512, D=512, V=1000. f32 inputs, f32 output.
// R23: gemm retiled 128x128 / 4 waves / BK=32 / triple-buffer 48 KiB so
// 3 blocks/CU co-reside (launch_bounds(256,3); 144<=160 KiB). R13-R20's
// five schedule variants were all ~2100cyc/phase mono-block lockstep --
// occupancy 13% showed the declared 2nd block never landed at 72-96 KiB.
// Independent-barrier co-resident blocks provide the inter-block overlap
// no intra-block schedule achieved. Same 0-conflict swizzle + counted
// vmcnt (4 loads/wave/group, stage t+2 at t, vmcnt(4), drain at t=14).
// Grid 1536 = 2 exact rounds at 3/CU. Scan = R22 (c-wave reg-hoist+
// setprio, 336us total companion). Everything else unchanged.

#define LAYERS 4
#define BB 32
#define TT 512
#define DD 512
#define N3 1536
#define MROWS (TT * BB)
#define WPL ((size_t)DD * N3)
#define SB 32                   // steps per phase (scan)
#define LOG2E 1.4426950408889634f
#define TWOLOG2E 2.8853900817779268f

typedef unsigned short u16;
typedef unsigned int u32;
typedef _Float16 half8 __attribute__((ext_vector_type(8)));
typedef float f32x4 __attribute__((ext_vector_type(4)));

#define SBAR() asm volatile("s_barrier" ::: "memory")
#define WAITVM(n) asm volatile("s_waitcnt vmcnt(" n ")" ::: "memory")

__device__ __forceinline__ float b2f(u16 u) {
  union { unsigned int i; float f; } x;
  x.i = ((unsigned int)u) << 16;
  return x.f;
}
__device__ __forceinline__ u16 f2h(float f) {
  _Float16 h = (_Float16)f;
  return *(u16*)&h;
}
__device__ __forceinline__ float h2f(u16 u) {
  _Float16 h;
  *(u16*)&h = u;
  return (float)h;
}
__device__ __forceinline__ float rcpf(float x) { return __builtin_amdgcn_rcpf(x); }
__device__ __forceinline__ float exp2f_(float x) { return __builtin_amdgcn_exp2f(x); }

__device__ __forceinline__ void async_ld16(const void* g, void* l) {
  __builtin_amdgcn_global_load_lds(
      (const __attribute__((address_space(1))) void*)g,
      (__attribute__((address_space(3))) void*)l, 16, 0, 0);
}
__device__ __forceinline__ void async_ld4(const void* g, void* l) {
  __builtin_amdgcn_global_load_lds(
      (const __attribute__((address_space(1))) void*)g,
      (__attribute__((address_space(3))) void*)l, 4, 0, 0);
}

// ---- dtype detection (flags[0]: floats f32, [1]: mask bytes, [2]: ids int64)
__global__ void detect_kernel(const u16* __restrict__ emb_u,
                              const int* __restrict__ mask_i,
                              const int* __restrict__ ids_i,
                              int* __restrict__ flags) {
  __shared__ int cnt[3];
  __shared__ int zc;
  int tid = threadIdx.x;
  if (tid < 3) cnt[tid] = 0;
  if (tid == 0) zc = 0;
  __syncthreads();
  int bad = 0, zero_even = 0;
  for (int i = tid; i < 8192; i += 256) {
    u16 u = emb_u[i];
    unsigned e = (u >> 7) & 0xFF;
    if (e >= 0x8F) bad++;
    if ((i & 1) == 0 && u == 0) zero_even++;
  }
  if (bad) atomicAdd(&cnt[0], bad);
  if (zero_even) atomicAdd(&zc, zero_even);
  if (tid < 64) {
    unsigned vv = (unsigned)mask_i[tid];
    if (vv > 1u) atomicAdd(&cnt[1], 1);
  }
  if (tid < 256) {
    if (ids_i[2 * tid + 1] == 0) atomicAdd(&cnt[2], 1);
  }
  __syncthreads();
  if (tid == 0) {
    flags[0] = (cnt[0] > 64 || zc > 3000) ? 1 : 0;
    flags[1] = (cnt[1] > 0) ? 1 : 0;
    flags[2] = (cnt[2] >= 192) ? 1 : 0;
  }
}

// ---- W -> f16 transpose: W16[l][n][k] ----------------------------------
__global__ __launch_bounds__(256)
void wprep_kernel(const void* __restrict__ W, u16* __restrict__ W16,
                  const int* __restrict__ flags) {
  __shared__ float tileW[32][33];
  int l = blockIdx.z;
  int k0 = blockIdx.x * 32;
  int n0 = blockIdx.y * 32;
  int tx = threadIdx.x & 31;
  int ty = threadIdx.x >> 5;
  int ff = flags[0];
  const float* Wf = (const float*)W + (size_t)l * WPL;
  const u16* Wb = (const u16*)W + (size_t)l * WPL;
  for (int kk = ty; kk < 32; kk += 8) {
    size_t off = (size_t)(k0 + kk) * N3 + n0 + tx;
    tileW[kk][tx] = ff ? Wf[off] : b2f(Wb[off]);
  }
  __syncthreads();
  u16* outP = W16 + (size_t)l * WPL;
  for (int nn = ty; nn < 32; nn += 8) {
    float x = tileW[tx][nn];
    outP[(size_t)(n0 + nn) * DD + k0 + tx] = f2h(x);
  }
}

// ---- embedding: X16 f16 (T,B,D) only -----------------------------------
__global__ void embed_kernel(const int* __restrict__ ids,
                             const void* __restrict__ emb,
                             u16* __restrict__ X16,
                             const int* __restrict__ flags) {
  int i = blockIdx.x * 256 + threadIdx.x;  // (t,b,d) linear
  int d = i & (DD - 1);
  int tb = i >> 9;
  int b = tb & (BB - 1);
  int t = tb >> 5;
  int ii = b * TT + t;
  int id = flags[2] ? ids[2 * ii] : ids[ii];
  float val = flags[0] ? ((const float*)emb)[id * DD + d]
                       : b2f(((const u16*)emb)[id * DD + d]);
  X16[i] = f2h(val);
}

// ---- MFMA fp16 GEMM: 128x128 tile, 4 waves, triple-buffer BK=32 --------
// 3 blocks/CU co-resident (48 KiB LDS, launch_bounds(256,3)): independent
// barriers let one block's MFMA fill another's LDS/wait stalls.
// Wave tile 64x64 = acc[4][4]. Per phase: 8 ds_read_b128 + stage(t+2)
// (4 loads/wave) + 16 MFMA + vmcnt(4) + s_barrier. Slot audit: stage(t+2)
// writes slot (t+2)%3 = tile t-1's slot, consumed before the barrier
// preceding the stage. Same measured-0-conflict 1KB-block swizzle.
__global__ __launch_bounds__(256, 3)
void gemm_kernel(const u16* __restrict__ X16, const u16* __restrict__ W16l,
                 const void* __restrict__ bvec, int layer,
                 const int* __restrict__ flags,
                 u16* __restrict__ U16, int row_base, int chunkM, int nblk) {
  __shared__ u16 ldsA[3][4096];  // [slot][8 blocks x 512 u16] = 24 KiB
  __shared__ u16 ldsB[3][4096];  // [slot][8 blocks x 512 u16] = 24 KiB
  const int tid = threadIdx.x;
  const int lane = tid & 63, wave = tid >> 6;
  const int wm = wave >> 1, wn = wave & 1;
  const int m16 = lane & 15, quad = lane >> 4;

  // bijective XCD swizzle (nblk % 8 == 0 for all chunk sizes)
  const int orig = blockIdx.x;
  const int wg = (orig & 7) * (nblk >> 3) + (orig >> 3);
  const int mt = wg / 12, nt = wg - mt * 12;

  const int arow0 = row_base + mt * 128;
  const int bcol0 = nt * 128;

  // staging: lane l -> row-in-block (l>>2), LDS chunk (l&3); global chunk
  // is the inverse swizzle q = (l&3) ^ ((l>>3)&3)
  const int srow = lane >> 2;
  const int sq = (lane & 3) ^ ((lane >> 3) & 3);
  const u16* pa = X16 + (size_t)(arow0 + wave * 32 + srow) * DD + sq * 8;
  const u16* pb = W16l + (size_t)(bcol0 + wave * 32 + srow) * DD + sq * 8;

  auto stage = [&](int t) {   // K-tile t -> slot t%3; 4 loads/wave (A2,B2)
    const int sl = t % 3;
    const int kv = t * 32;
    async_ld16(pa + kv, &ldsA[sl][(2 * wave) * 512]);
    async_ld16(pa + kv + (size_t)16 * DD, &ldsA[sl][(2 * wave + 1) * 512]);
    async_ld16(pb + kv, &ldsB[sl][(2 * wave) * 512]);
    async_ld16(pb + kv + (size_t)16 * DD, &ldsB[sl][(2 * wave + 1) * 512]);
  };

  f32x4 acc[4][4];
#pragma unroll
  for (int mi = 0; mi < 4; ++mi)
#pragma unroll
    for (int ni = 0; ni < 4; ++ni)
#pragma unroll
      for (int r = 0; r < 4; ++r) acc[mi][ni][r] = 0.f;

  stage(0); stage(1);
  WAITVM("4");   // tile 0 landed (tile 1 in flight)
  SBAR();

  // fragment read: lane (m16, quad) -> row m16, LDS chunk quad^((m16>>1)&3)
  const int loff = m16 * 32 + (quad ^ ((m16 >> 1) & 3)) * 8;

#pragma unroll
  for (int t = 0; t < 16; ++t) {
    const int sl = t % 3;
    half8 af[4], bf[4];
#pragma unroll
    for (int i = 0; i < 4; ++i) {
      af[i] = *(const half8*)&ldsA[sl][(wm * 4 + i) * 512 + loff];
      bf[i] = *(const half8*)&ldsB[sl][(wn * 4 + i) * 512 + loff];
    }
    if (t + 2 < 16) stage(t + 2);
    __builtin_amdgcn_s_setprio(1);
#pragma unroll
    for (int mi = 0; mi < 4; ++mi)
#pragma unroll
      for (int ni = 0; ni < 4; ++ni)
        acc[mi][ni] = __builtin_amdgcn_mfma_f32_16x16x32_f16(
            af[mi], bf[ni], acc[mi][ni], 0, 0, 0);
    __builtin_amdgcn_s_setprio(0);
    if (t <= 13) WAITVM("4");        // tile t+1 landed (t+2 in flight)
    else if (t == 14) WAITVM("0");   // last tile landed
    if (t < 15) SBAR();
  }

  // epilogue: plane and transform are block-uniform (128-col tile)
  const int ff = flags[0];
  const int pl = nt >> 2;               // plane 0..2
  const int dd0 = (nt & 3) * 128;
  u16* up = U16 + (size_t)pl * chunkM * 512;
  const int r0 = mt * 128 + wm * 64 + quad * 4;
  const int c0 = dd0 + wn * 64 + m16;
  if (pl == 0) {
#pragma unroll
    for (int mi = 0; mi < 4; ++mi)
#pragma unroll
      for (int reg = 0; reg < 4; ++reg) {
        size_t rb = (size_t)(r0 + mi * 16 + reg) * 512 + c0;
#pragma unroll
        for (int ni = 0; ni < 4; ++ni)
          up[rb + ni * 16] = f2h(acc[mi][ni][reg]);
      }
  } else {
    float bias[4];
#pragma unroll
    for (int ni = 0; ni < 4; ++ni) {
      size_t bo = (size_t)layer * 2 * DD + (size_t)(pl - 1) * DD + c0 + ni * 16;
      bias[ni] = ff ? ((const float*)bvec)[bo] : b2f(((const u16*)bvec)[bo]);
    }
#pragma unroll
    for (int mi = 0; mi < 4; ++mi)
#pragma unroll
      for (int reg = 0; reg < 4; ++reg) {
        size_t rb = (size_t)(r0 + mi * 16 + reg) * 512 + c0;
#pragma unroll
        for (int ni = 0; ni < 4; ++ni)
          up[rb + ni * 16] = f2h(-(acc[mi][ni][reg] + bias[ni]) * LOG2E);
      }
  }
}

// ---- SRU scan: split-recurrence, 7 waves; c-wave register-hoisted ------
// (R22 verbatim: c-wave LDS reads hoisted to VGPRs + setprio on chain.)
template <int EMIT>
__global__ __launch_bounds__(448, 1)
void scan_kernel(const u16* __restrict__ U16, float* __restrict__ X,
                 u16* __restrict__ X16,
                 const void* __restrict__ mask_p, const void* __restrict__ vbase,
                 int layer, const int* __restrict__ flags,
                 float* __restrict__ carry, int t0, int nt, int chunkM) {
  __shared__ u16 bufA[2][2][SB][64];   // [parity][xt|fps][step][lane]
  __shared__ u16 bufB[3][2][SB][64];   // [k%3][rps|xi][step][lane]
  __shared__ float ring[2][2][SB][64]; // [parity][cprev|cn][step][lane]
  __shared__ int msk[TT];
  const int tid = threadIdx.x;
  const int wave = tid >> 6, lane = tid & 63;
  const int idx0 = blockIdx.x * 64;  // chain base in [0, B*D)
  const int b = idx0 >> 9;           // one b per block
  const int d0 = idx0 & 511;
  const int ff = flags[0], fm = flags[1];

  const int* mi_ = (const int*)mask_p + b * TT;
  const unsigned char* mb_ = (const unsigned char*)mask_p + b * TT;
  for (int i = tid; i < nt; i += 448) msk[i] = fm ? (int)mb_[t0 + i] : mi_[t0 + i];

  float vfs = 0.f, vrs = 0.f, c = 0.f;
  {
    int d = d0 + lane;
    size_t voff = (size_t)layer * 2 * DD;
    if (wave == 0) {
      float vf = ff ? ((const float*)vbase)[voff + d]
                    : b2f(((const u16*)vbase)[voff + d]);
      vfs = -vf * LOG2E;
      c = (t0 == 0) ? 0.f : carry[idx0 + lane];
    } else if (wave >= 1 && wave <= 4) {
      float vr = ff ? ((const float*)vbase)[voff + DD + d]
                    : b2f(((const u16*)vbase)[voff + DD + d]);
      vrs = -vr * LOG2E;
    }
  }

  const int nbuf = nt / SB;

  // u16-stream pair load: lanes 0-31 -> step s, lanes 32-63 -> step s+1
  auto ld_pair = [&](const u16* rowS, const u16* rowS1, void* ldst) {
    const u32* a0 = (const u32*)rowS;
    const u32* a1 = (const u32*)rowS1;
    const u32* ga = (lane < 32) ? (a0 + lane) : (a1 + (lane - 32));
    async_ld4(ga, ldst);
  };

  auto produceA = [&](int k) {  // wave5: xt (plane0) + fps (plane1)
    int ph = k & 1, tl = k * SB;
    const u16* p0 = U16 + ((size_t)tl * BB + b) * 512 + d0;
    const u16* p1 = p0 + (size_t)chunkM * 512;
#pragma unroll
    for (int s = 0; s < SB; s += 2)
      ld_pair(p0 + (size_t)s * BB * 512, p0 + (size_t)(s + 1) * BB * 512,
              &bufA[ph][0][s][0]);
#pragma unroll
    for (int s = 0; s < SB; s += 2)
      ld_pair(p1 + (size_t)s * BB * 512, p1 + (size_t)(s + 1) * BB * 512,
              &bufA[ph][1][s][0]);
  };
  auto produceB = [&](int k) {  // wave6: rps (plane2) + xi (X16)
    int ph = k % 3, tl = k * SB;
    const u16* p2 = U16 + 2 * (size_t)chunkM * 512 + ((size_t)tl * BB + b) * 512 + d0;
    const u16* xb = X16 + ((size_t)(t0 + tl) * BB + b) * DD + d0;
#pragma unroll
    for (int s = 0; s < SB; s += 2)
      ld_pair(p2 + (size_t)s * BB * 512, p2 + (size_t)(s + 1) * BB * 512,
              &bufB[ph][0][s][0]);
#pragma unroll
    for (int s = 0; s < SB; s += 2)
      ld_pair(xb + (size_t)s * BB * DD, xb + (size_t)(s + 1) * BB * DD,
              &bufB[ph][1][s][0]);
  };

  float* Xp = X + (size_t)b * TT * DD + d0 + lane;

  // h-wave hw (0..3) handles steps [hw*8, hw*8+8) of phase j
  auto hphase = [&](int j, int hw) {
    int phc = j & 1, phb = j % 3;
    int sbase = hw * (SB / 4);
#pragma unroll
    for (int si = 0; si < SB / 4; ++si) {
      int s = sbase + si;
      float cprev = ring[phc][0][s][lane];
      float cn = ring[phc][1][s][lane];
      float rps = h2f(bufB[phb][0][s][lane]);
      float xin = h2f(bufB[phb][1][s][lane]);
      int m = msk[j * SB + s];
      float tr = exp2f_(fmaf(vrs, cprev, rps));
      float r = rcpf(1.f + tr);
      float e2 = exp2f_(cn * TWOLOG2E);
      float th = fmaf(-2.f, rcpf(e2 + 1.f), 1.f);
      float h = fmaf(r, th - xin, xin);
      float hout = (m == 0) ? 0.f : h;
      int tg = t0 + j * SB + s;
      if (EMIT)
        X16[((size_t)tg * BB + b) * DD + d0 + lane] = f2h(hout);
      else
        Xp[(size_t)tg * DD] = hout;
    }
  };

  if (wave == 5) produceA(0);
  if (wave == 6) produceB(0);

  for (int k = 0; k < nbuf; ++k) {
    __syncthreads();  // phase-k operands ready; ring[k-1] ready
    if (wave == 5) {
      if (k + 1 < nbuf) produceA(k + 1);
    } else if (wave == 6) {
      if (k + 1 < nbuf) produceB(k + 1);
    } else if (wave == 0) {
      const int ph = k & 1;
      // hoist ALL of this phase's LDS reads into registers (compile-time
      // indices -> VGPRs), so the serial chain below is register-only
      // except the non-blocking ring ds_writes.
      float xtv[SB], fpv[SB];
      int mv[SB];
#pragma unroll
      for (int s = 0; s < SB; ++s) {
        xtv[s] = h2f(bufA[ph][0][s][lane]);
        fpv[s] = h2f(bufA[ph][1][s][lane]);
        mv[s] = msk[k * SB + s];
      }
      __builtin_amdgcn_s_setprio(1);
#pragma unroll
      for (int s = 0; s < SB; ++s) {
        float t = exp2f_(fmaf(vfs, c, fpv[s]));
        float f = rcpf(1.f + t);
        float cn = fmaf(f, c - xtv[s], xtv[s]);
        ring[ph][0][s][lane] = c;
        ring[ph][1][s][lane] = cn;
        c = (mv[s] == 0) ? c : cn;
      }
      __builtin_amdgcn_s_setprio(0);
    } else {  // waves 1-4: h path
      if (k > 0) hphase(k - 1, wave - 1);
    }
  }
  __syncthreads();  // last ring phase visible
  if (wave >= 1 && wave <= 4) hphase(nbuf - 1, wave - 1);
  if (wave == 0) carry[idx0 + lane] = c;
}

__global__ void sentinel_kernel(float* out) { out[threadIdx.x] = 12345.f; }

extern "C" void kernel_launch(void* const* d_in, const int* in_sizes, int n_in,
                              void* d_out, int out_size, void* d_ws, size_t ws_size,
                              hipStream_t stream) {
  const int* ids = (const int*)d_in[0];
  const void* mask = d_in[1];
  const void* emb = d_in[2];
  const void* W = d_in[3];
  const void* v = d_in[4];
  const void* bp = d_in[5];

  char* ws = (char*)d_ws;
  int* flags = (int*)ws;                      // 4 KiB
  float* carry = (float*)(ws + 4096);         // 64 KiB
  const size_t offX16 = 69632;
  const size_t offW16 = offX16 + (size_t)MROWS * DD * 2;   // +16 MiB
  const size_t offU = offW16 + (size_t)LAYERS * WPL * 2;   // +6 MiB
  const size_t perT = (size_t)BB * N3 * 2;    // 98304 B / timestep (3 f16 planes)

  const int cand[4] = {512, 256, 128, 64};  // multiples of 2*SB
  int chunkT = 0;
  for (int i = 0; i < 4; ++i) {
    if (ws_size >= offU + (size_t)cand[i] * perT) { chunkT = cand[i]; break; }
  }
  if (!chunkT) {
    sentinel_kernel<<<1, 256, 0, stream>>>((float*)d_out);
    return;
  }
  const int chunkM = chunkT * BB;

  u16* X16 = (u16*)(ws + offX16);
  u16* W16 = (u16*)(ws + offW16);
  u16* U16 = (u16*)(ws + offU);
  float* X = (float*)d_out;  // (B,T,D) f32 — final output only

  detect_kernel<<<1, 256, 0, stream>>>((const u16*)emb, (const int*)mask,
                                       (const int*)ids, flags);
  wprep_kernel<<<dim3(16, 48, 4), 256, 0, stream>>>(W, W16, flags);
  embed_kernel<<<MROWS * DD / 256, 256, 0, stream>>>(ids, emb, X16, flags);

  int nch = TT / chunkT;
  for (int l = 0; l < LAYERS; ++l) {
    const u16* W16l = W16 + (size_t)l * WPL;
    for (int ch = 0; ch < nch; ++ch) {
      int t0 = ch * chunkT;
      int nblk = (chunkM / 128) * 12;   // 128x128 tiles; % 8 == 0 always
      gemm_kernel<<<nblk, 256, 0, stream>>>(X16, W16l, bp, l, flags, U16,
                                            t0 * BB, chunkM, nblk);
      if (l < LAYERS - 1)
        scan_kernel<1><<<BB * DD / 64, 448, 0, stream>>>(U16, X, X16, mask, v, l,
                                                         flags, carry, t0, chunkT,
                                                         chunkM);
      else
        scan_kernel<0><<<BB * DD / 64, 448, 0, stream>>>(U16, X, X16, mask, v, l,
                                                         flags, carry, t0, chunkT,
                                                         chunkM);
    }
  }
}